// Round 3
// baseline (105.610 us; speedup 1.0000x reference)
//
#include <hip/hip_runtime.h>
#include <hip/hip_bf16.h>

// ExpertLinear: y[b,o] = sum_e ew[b,e] * (W[e,o,:].x[b,:] + bias[e,o])
// B=512, E=8, IN=OUT=1024.
//
// R3 structure:
//  - prep_x: x fp32 -> bf16 in ws (3 MB traffic; ws poison is unconditional
//    harness overhead, so using ws is free).
//  - gemm_fused: TM=256 batch rows x TN=64 W-rows (8 out-cols x 8 experts),
//    BK=64, grid 128x2 = 256 blocks, 512 threads (8 waves), 1 block/CU.
//    * W read as fp32 ~once from HBM (32 MB): each W row needed by 2 m-blocks,
//      which land on the same XCD under %8 round-robin -> L2 hit.
//    * A staged bf16 via global_load_lds width=16 (no VALU conversion).
//    * B (W slice) converted in-register: only 8 floats/thread/iter.
//    * Double-buffered LDS (80 KB), one barrier/iter; next-tile loads issued
//      before the MFMA phase so latency hides behind ~620 MFMA cycles.
//    * Expert blend in epilogue; experts split across lane halves (l15>>3),
//      combined with one __shfl_xor(p, 8).

#define EDIM 8
#define INDIM 1024
#define OUTDIM 1024
#define BATCH 512
#define TM 256
#define TNR 64            // B-tile rows = 8 out-cols x 8 experts
#define BK 64
#define NITER (INDIM / BK)  // 16

typedef __attribute__((ext_vector_type(8))) short frag8;   // 8 bf16 (4 VGPRs)
typedef __attribute__((ext_vector_type(4))) float f32x4;   // MFMA C/D

__device__ inline void async_ld16(void* lds, const void* g) {
  __builtin_amdgcn_global_load_lds(
      (const __attribute__((address_space(1))) void*)g,
      (__attribute__((address_space(3))) void*)lds, 16, 0, 0);
}

__device__ inline ushort f2bf(float f) {
  unsigned u = __builtin_bit_cast(unsigned, f);
  u += 0x7fffu + ((u >> 16) & 1u);   // round-to-nearest-even
  return (ushort)(u >> 16);
}

__device__ inline ushort4 f4_to_bf4(float4 v) {
  ushort4 o;
  o.x = f2bf(v.x); o.y = f2bf(v.y); o.z = f2bf(v.z); o.w = f2bf(v.w);
  return o;
}

// ---- pass 1: x fp32 -> bf16 (131072 float4 groups) ----
__global__ __launch_bounds__(256) void prep_x(const float* __restrict__ x,
                                              ushort* __restrict__ wsX) {
  int i = blockIdx.x * 256 + threadIdx.x;
  float4 v = ((const float4*)x)[i];
  ((ushort4*)wsX)[i] = f4_to_bf4(v);
}

// ---- pass 2: fused GEMM + expert blend ----
__global__ __launch_bounds__(512) void gemm_fused(
    const ushort* __restrict__ Xb,   // bf16 x [512][1024]
    const float* __restrict__ ew,    // [512][8]
    const float* __restrict__ W,     // [8][1024][1024] fp32
    const float* __restrict__ bias,  // [8][1024]
    float* __restrict__ out) {       // [512][1024]
  __shared__ __align__(16) ushort As[2][TM * BK];   // 2 x 32 KB
  __shared__ __align__(16) ushort Bs[2][TNR * BK];  // 2 x 8 KB

  const int tid  = threadIdx.x;
  const int lane = tid & 63;
  const int wave = tid >> 6;              // 0..7
  const int o0 = blockIdx.x * 8;          // out-col base (0..1016)
  const int m0 = blockIdx.y * TM;         // 0 or 256

  const int l15  = lane & 15;
  const int quad = lane >> 4;

  // A staging: chunk = 8 rows x 64 cols bf16 = 1 KB, lane -> (row=lane>>3,
  // 16B slot=lane&7). 32 chunks/iter, 4 per wave. LDS layout row-major r*64+k.
  const ushort* aG = Xb + (size_t)(m0 + (lane >> 3)) * INDIM + (lane & 7) * 8;

  // B staging: 64 rows x 16 float4 slots; thread covers fi = tid, tid+512.
  int fi0 = tid, fi1 = tid + 512;
  int r0 = fi0 >> 4, s0 = fi0 & 15;
  int r1 = fi1 >> 4, s1 = fi1 & 15;
  const float* bG0 = W + (size_t)((r0 >> 3) * 1024 + o0 + (r0 & 7)) * INDIM + s0 * 4;
  const float* bG1 = W + (size_t)((r1 >> 3) * 1024 + o0 + (r1 & 7)) * INDIM + s1 * 4;
  ushort* bW0base = &Bs[0][0] + r0 * BK + s0 * 4;   // buf stride = TNR*BK
  ushort* bW1base = &Bs[0][0] + r1 * BK + s1 * 4;

  f32x4 acc[2][4] = {};

  // ---- prologue: stage iter 0 ----
#pragma unroll
  for (int cc = 0; cc < 4; ++cc) {
    const int c = wave * 4 + cc;
    async_ld16(&As[0][c * 512], aG + (size_t)c * 8 * INDIM);
  }
  {
    float4 v0 = *(const float4*)bG0;
    float4 v1 = *(const float4*)bG1;
    *(ushort4*)bW0base = f4_to_bf4(v0);
    *(ushort4*)bW1base = f4_to_bf4(v1);
  }
  __syncthreads();

  for (int it = 0; it < NITER; ++it) {
    const int cur = it & 1, nxt = cur ^ 1;
    const bool more = (it + 1 < NITER);
    float4 v0, v1;
    if (more) {
      const int k0n = (it + 1) * BK;
      // async A loads into the other buffer -- in flight across the MFMA phase
#pragma unroll
      for (int cc = 0; cc < 4; ++cc) {
        const int c = wave * 4 + cc;
        async_ld16(&As[nxt][c * 512], aG + (size_t)c * 8 * INDIM + k0n);
      }
      v0 = *(const float4*)(bG0 + k0n);
      v1 = *(const float4*)(bG1 + k0n);
    }

    // ---- MFMA phase over buffer `cur` ----
#pragma unroll
    for (int kk = 0; kk < BK; kk += 32) {
      frag8 a[2], b[4];
#pragma unroll
      for (int i = 0; i < 2; ++i)
        a[i] = *(const frag8*)&As[cur][(wave * 32 + i * 16 + l15) * BK + kk + quad * 8];
#pragma unroll
      for (int j = 0; j < 4; ++j)
        b[j] = *(const frag8*)&Bs[cur][(j * 16 + l15) * BK + kk + quad * 8];
#pragma unroll
      for (int i = 0; i < 2; ++i)
#pragma unroll
        for (int j = 0; j < 4; ++j)
          acc[i][j] = __builtin_amdgcn_mfma_f32_16x16x32_bf16(a[i], b[j], acc[i][j], 0, 0, 0);
    }

    if (more) {
      // convert + write next B tile (compiler waits vmcnt here, after MFMA)
      *(ushort4*)(bW0base + nxt * (TNR * BK)) = f4_to_bf4(v0);
      *(ushort4*)(bW1base + nxt * (TNR * BK)) = f4_to_bf4(v1);
    }
    __syncthreads();   // drains async A loads + B ds_writes; guards buffer swap
  }

  // ---- epilogue: blend experts + bias ----
  // acc[i][j] col l15 -> B-row j*16+l15 -> expert 2j + (l15>>3), oc o0+(l15&7)
  const int h  = l15 >> 3;
  const int oc = o0 + (l15 & 7);
  float bgather[4];
#pragma unroll
  for (int j = 0; j < 4; ++j) bgather[j] = bias[(2 * j + h) * OUTDIM + oc];

#pragma unroll
  for (int i = 0; i < 2; ++i) {
#pragma unroll
    for (int r = 0; r < 4; ++r) {
      const int b = m0 + wave * 32 + i * 16 + quad * 4 + r;
      float p = 0.f;
#pragma unroll
      for (int j = 0; j < 4; ++j)
        p += ew[b * EDIM + 2 * j + h] * (acc[i][j][r] + bgather[j]);
      p += __shfl_xor(p, 8, 64);   // combine even/odd expert halves
      if (h == 0) out[(size_t)b * OUTDIM + oc] = p;
    }
  }
}

// ---- fallback (ws too small): naive fp32, correct but slow ----
__global__ __launch_bounds__(256) void fallback_kernel(
    const float* __restrict__ x, const float* __restrict__ ew,
    const float* __restrict__ W, const float* __restrict__ bias,
    float* __restrict__ out) {
  int idx = blockIdx.x * 256 + threadIdx.x;
  int b = idx >> 10;
  int o = idx & 1023;
  float y = 0.f;
  for (int k = 0; k < EDIM; ++k) {
    const float* wr = W + ((size_t)k * OUTDIM + o) * INDIM;
    const float* xr = x + (size_t)b * INDIM;
    float dot = 0.f;
    for (int i = 0; i < INDIM; ++i) dot += wr[i] * xr[i];
    y += ew[k + b * EDIM] * (dot + bias[k * OUTDIM + o]);
  }
  out[idx] = y;
}

extern "C" void kernel_launch(void* const* d_in, const int* in_sizes, int n_in,
                              void* d_out, int out_size, void* d_ws, size_t ws_size,
                              hipStream_t stream) {
  const float* x    = (const float*)d_in[0];
  const float* ew   = (const float*)d_in[1];
  const float* W    = (const float*)d_in[2];
  const float* bias = (const float*)d_in[3];
  float* out = (float*)d_out;

  if (ws_size < (size_t)(BATCH * INDIM * 2)) {   // 1 MB for bf16 x
    fallback_kernel<<<2048, 256, 0, stream>>>(x, ew, W, bias, out);
    return;
  }
  ushort* wsX = (ushort*)d_ws;

  prep_x<<<512, 256, 0, stream>>>(x, wsX);
  gemm_fused<<<dim3(OUTDIM / 8, BATCH / TM), 512, 0, stream>>>(
      wsX, ew, W, bias, out);
}

// Round 4
// 99.816 us; speedup vs baseline: 1.0581x; 1.0581x over previous
//
#include <hip/hip_runtime.h>
#include <hip/hip_bf16.h>

// ExpertLinear: y[b,o] = sum_e ew[b,e] * (W[e,o,:].x[b,:] + bias[e,o])
// B=512, E=8, IN=OUT=1024.
//
// R4:
//  - prep_x: x fp32 -> bf16 in ws (halves A traffic, zero A-convert VALU).
//  - gemm_fused: TM=128 x TN=64 (8 out-cols x 8 experts), BK=64,
//    grid 128x4 = 512 blocks x 256 thr (4 waves) -> 2 blocks/CU: independent
//    barrier domains overlap the vmcnt-drain stall (m114).
//  - XOR-swizzled LDS: logical 16B k-slot s of row r stored at slot s^(r&7).
//    For global_load_lds this is a lane->global-address permutation (LDS dst
//    stays lane-contiguous so async works); frag ds_read_b128 then hits all
//    8 bank-groups uniformly (2 lanes each = free) instead of 16-way on
//    banks 0-3 (the unpadded m97 conflict, m98: 1.7e7 SQ_LDS_BANK_CONFLICT).
//  - W fp32 read ~once from HBM: the 4 m-partners of an n-tile are dispatch
//    ids x+128k -> same XCD under %8 round-robin -> partner reads hit L2.
//  - Expert blend in epilogue: frag j = experts {2j,2j+1} split by l15>>3,
//    combined with one __shfl_xor(p,8).

#define EDIM 8
#define INDIM 1024
#define OUTDIM 1024
#define BATCH 512
#define TM 128
#define TNR 64
#define BK 64
#define NITER (INDIM / BK)  // 16

typedef __attribute__((ext_vector_type(8))) short frag8;   // 8 bf16 (4 VGPRs)
typedef __attribute__((ext_vector_type(4))) float f32x4;   // MFMA C/D

__device__ inline void async_ld16(void* lds, const void* g) {
  __builtin_amdgcn_global_load_lds(
      (const __attribute__((address_space(1))) void*)g,
      (__attribute__((address_space(3))) void*)lds, 16, 0, 0);
}

__device__ inline ushort f2bf(float f) {
  unsigned u = __builtin_bit_cast(unsigned, f);
  u += 0x7fffu + ((u >> 16) & 1u);   // round-to-nearest-even
  return (ushort)(u >> 16);
}

__device__ inline ushort4 f4_to_bf4(float4 v) {
  ushort4 o;
  o.x = f2bf(v.x); o.y = f2bf(v.y); o.z = f2bf(v.z); o.w = f2bf(v.w);
  return o;
}

// ---- pass 1: x fp32 -> bf16 (131072 float4 groups) ----
__global__ __launch_bounds__(256) void prep_x(const float* __restrict__ x,
                                              ushort* __restrict__ wsX) {
  int i = blockIdx.x * 256 + threadIdx.x;
  ((ushort4*)wsX)[i] = f4_to_bf4(((const float4*)x)[i]);
}

// ---- pass 2: fused GEMM + expert blend ----
__global__ __launch_bounds__(256, 2) void gemm_fused(
    const ushort* __restrict__ Xb,   // bf16 x [512][1024]
    const float* __restrict__ ew,    // [512][8]
    const float* __restrict__ W,     // [8][1024][1024] fp32
    const float* __restrict__ bias,  // [8][1024]
    float* __restrict__ out) {       // [512][1024]
  // row r of a tile: 64 ushorts; logical k-slot s (16B) at ushort
  // r*64 + (s^(r&7))*8
  __shared__ __align__(16) ushort As[2 * TM * BK];   // 32 KB
  __shared__ __align__(16) ushort Bs[2 * TNR * BK];  // 16 KB

  const int tid  = threadIdx.x;
  const int lane = tid & 63;
  const int wave = tid >> 6;              // 0..3
  const int o0 = blockIdx.x * 8;          // out-col base
  const int m0 = blockIdx.y * TM;         // 0,128,256,384

  const int l15  = lane & 15;
  const int quad = lane >> 4;

  // ---- A async staging: 16 chunks (8 rows x 64 cols = 1 KB), 4 per wave.
  // lane -> row-in-chunk = lane>>3, physical slot = lane&7; global k-slot
  // fetched = (lane&7) ^ row  (so logical slot s lands at s^(r&7)).
  const int arow   = lane >> 3;
  const int akslot = (lane & 7) ^ arow;
  const ushort* aG = Xb + (size_t)(m0 + arow) * INDIM + akslot * 8;

  // ---- B staging: 64 rows x 16 float4 slots, 4 per thread ----
  const float* bG[4];
  int bWoff[4];
#pragma unroll
  for (int p = 0; p < 4; ++p) {
    int fi = tid + 256 * p;
    int rb = fi >> 4, gs = fi & 15;
    // B-tile row rb -> expert rb>>3, out-col o0+(rb&7)
    bG[p] = W + (size_t)((rb >> 3) * 1024 + o0 + (rb & 7)) * INDIM + gs * 4;
    // fp32 slot gs -> bf16 k-slot gs>>1, half gs&1; swizzled
    bWoff[p] = rb * 64 + (((gs >> 1) ^ (rb & 7)) * 8) + (gs & 1) * 4;
  }

  f32x4 acc[2][4] = {};

  // ---- prologue: stage iter 0 ----
#pragma unroll
  for (int cc = 0; cc < 4; ++cc) {
    int c = wave * 4 + cc;
    async_ld16(&As[c * 512], aG + (size_t)c * 8 * INDIM);
  }
#pragma unroll
  for (int p = 0; p < 4; ++p)
    *(ushort4*)&Bs[bWoff[p]] = f4_to_bf4(*(const float4*)bG[p]);
  __syncthreads();

  for (int it = 0; it < NITER; ++it) {
    const int cur = it & 1, nxt = cur ^ 1;
    const bool more = (it + 1 < NITER);
    float4 bv[4];
    if (more) {
      const int kn = (it + 1) * BK;
      // next-tile loads in flight across the MFMA phase
#pragma unroll
      for (int cc = 0; cc < 4; ++cc) {
        int c = wave * 4 + cc;
        async_ld16(&As[nxt * (TM * BK) + c * 512],
                   aG + (size_t)c * 8 * INDIM + kn);
      }
#pragma unroll
      for (int p = 0; p < 4; ++p) bv[p] = *(const float4*)(bG[p] + kn);
    }

    // ---- MFMA phase on buffer `cur` ----
#pragma unroll
    for (int kk8 = 0; kk8 < 8; kk8 += 4) {   // k-slot base (kk = kk8*8 elems)
      frag8 a[2], b[4];
#pragma unroll
      for (int i = 0; i < 2; ++i) {
        int ra = wave * 32 + i * 16 + l15;
        a[i] = *(const frag8*)&As[cur * (TM * BK) + ra * 64 +
                                  (((quad + kk8) ^ (ra & 7)) * 8)];
      }
#pragma unroll
      for (int j = 0; j < 4; ++j) {
        int rb = j * 16 + l15;
        b[j] = *(const frag8*)&Bs[cur * (TNR * BK) + rb * 64 +
                                  (((quad + kk8) ^ (rb & 7)) * 8)];
      }
#pragma unroll
      for (int i = 0; i < 2; ++i)
#pragma unroll
        for (int j = 0; j < 4; ++j)
          acc[i][j] = __builtin_amdgcn_mfma_f32_16x16x32_bf16(a[i], b[j], acc[i][j], 0, 0, 0);
    }

    if (more) {
      // convert + write next B tile (vmcnt wait lands here, after MFMA)
#pragma unroll
      for (int p = 0; p < 4; ++p)
        *(ushort4*)&Bs[nxt * (TNR * BK) + bWoff[p]] = f4_to_bf4(bv[p]);
    }
    __syncthreads();   // drains async A + orders B writes; guards buffer swap
  }

  // ---- epilogue: blend experts + bias ----
  // C/D: col=l15 -> B-row j*16+l15 -> expert 2j+(l15>>3), oc=o0+(l15&7);
  // row = quad*4 + r within frag-tile.
  const int h  = l15 >> 3;
  const int oc = o0 + (l15 & 7);
  float bg[4];
#pragma unroll
  for (int j = 0; j < 4; ++j) bg[j] = bias[(2 * j + h) * OUTDIM + oc];

#pragma unroll
  for (int i = 0; i < 2; ++i) {
#pragma unroll
    for (int r = 0; r < 4; ++r) {
      const int b = m0 + wave * 32 + i * 16 + quad * 4 + r;
      float p = 0.f;
#pragma unroll
      for (int j = 0; j < 4; ++j)
        p += ew[b * EDIM + 2 * j + h] * (acc[i][j][r] + bg[j]);
      p += __shfl_xor(p, 8, 64);   // combine even/odd expert halves
      if (h == 0) out[(size_t)b * OUTDIM + oc] = p;
    }
  }
}

// ---- fallback (ws too small): naive fp32, correct but slow ----
__global__ __launch_bounds__(256) void fallback_kernel(
    const float* __restrict__ x, const float* __restrict__ ew,
    const float* __restrict__ W, const float* __restrict__ bias,
    float* __restrict__ out) {
  int idx = blockIdx.x * 256 + threadIdx.x;
  int b = idx >> 10;
  int o = idx & 1023;
  float y = 0.f;
  for (int k = 0; k < EDIM; ++k) {
    const float* wr = W + ((size_t)k * OUTDIM + o) * INDIM;
    const float* xr = x + (size_t)b * INDIM;
    float dot = 0.f;
    for (int i = 0; i < INDIM; ++i) dot += wr[i] * xr[i];
    y += ew[b * EDIM + k] * (dot + bias[k * OUTDIM + o]);
  }
  out[idx] = y;
}

extern "C" void kernel_launch(void* const* d_in, const int* in_sizes, int n_in,
                              void* d_out, int out_size, void* d_ws, size_t ws_size,
                              hipStream_t stream) {
  const float* x    = (const float*)d_in[0];
  const float* ew   = (const float*)d_in[1];
  const float* W    = (const float*)d_in[2];
  const float* bias = (const float*)d_in[3];
  float* out = (float*)d_out;

  if (ws_size < (size_t)(BATCH * INDIM * 2)) {   // 1 MB for bf16 x
    fallback_kernel<<<2048, 256, 0, stream>>>(x, ew, W, bias, out);
    return;
  }
  ushort* wsX = (ushort*)d_ws;

  prep_x<<<512, 256, 0, stream>>>(x, wsX);
  gemm_fused<<<dim3(OUTDIM / 8, BATCH / TM), 256, 0, stream>>>(
      wsX, ew, W, bias, out);
}